// Round 2
// baseline (5346.830 us; speedup 1.0000x reference)
//
#include <hip/hip_runtime.h>
#include <stdint.h>

// Problem dims
constexpr int Bsz  = 4096;
constexpr int Tst  = 20;
constexpr int Fin  = 2000;
constexpr int H1   = 512;
constexpr int H2   = 128;
constexpr int NOUT = 10;

constexpr int FW = 64;                    // padded words per spike row (2000 bits -> 63 words, pad to 64)
constexpr int CHUNK = 1024;               // batch rows per layer-1 chunk

// ---------------- Threefry-2x32-20, key = jax.random.key(1) = [0,1] ----------------
__device__ __forceinline__ void tf2x32(uint32_t c0, uint32_t c1, uint32_t& o0, uint32_t& o1) {
  const uint32_t k0 = 0u, k1 = 1u, k2 = 0x1BD11BDBu; // 0 ^ 1 ^ 0x1BD11BDA
  uint32_t x0 = c0 + k0;
  uint32_t x1 = c1 + k1;
#define ROTL(x,d) (((x)<<(d))|((x)>>(32-(d))))
#define RND(r) { x0 += x1; x1 = ROTL(x1,(r)) ^ x0; }
  RND(13) RND(15) RND(26) RND(6)   x0 += k1; x1 += k2 + 1u;
  RND(17) RND(29) RND(16) RND(24)  x0 += k2; x1 += k0 + 2u;
  RND(13) RND(15) RND(26) RND(6)   x0 += k0; x1 += k1 + 3u;
  RND(17) RND(29) RND(16) RND(24)  x0 += k1; x1 += k2 + 4u;
  RND(13) RND(15) RND(26) RND(6)   x0 += k2; x1 += k0 + 5u;
#undef RND
#undef ROTL
  o0 = x0; o1 = x1;
}

// JAX >= 0.4.36 default: threefry_partitionable=True.
// random_bits(32, shape): per flat element i (uint64 iota), counter = (hi32(i), lo32(i)) = (0, i),
// bits = out0 ^ out1. uniform = bitcast((bits>>9)|0x3f800000) - 1.0f; bernoulli = u < p.
// Spike bit (b,t,f) stored at word (b*T+t)*FW + f/32, bit f%32.
__global__ void spikegen(const float* __restrict__ x, uint32_t* __restrict__ sbits) {
  int gid = blockIdx.x * blockDim.x + threadIdx.x;  // 81920*64 threads
  if (gid >= Bsz * Tst * FW) return;
  int w = gid & 63;
  int row = gid >> 6;                 // b*T + t
  int b = row / Tst;
  uint32_t bits = 0;
  int fbase = w * 32;
  const float* xr = x + (size_t)b * Fin;
  uint32_t ibase = (uint32_t)row * (uint32_t)Fin;
  for (int j = 0; j < 32; ++j) {
    int f = fbase + j;
    if (f >= Fin) break;
    uint32_t o0, o1;
    tf2x32(0u, ibase + (uint32_t)f, o0, o1);
    uint32_t m = o0 ^ o1;
    float u = __uint_as_float((m >> 9) | 0x3f800000u) - 1.0f;
    if (u < xr[f]) bits |= (1u << j);
  }
  sbits[(size_t)row * FW + w] = bits;
}

// Generic bit-matrix (rows of packed spike bits) x f32 weight^T GEMM, f64 accumulation.
// C[r][o] = sum_f A[r][f] * Bmat[o][f]  + bias[o]
// Tile: 64 rows x 64 cols, 256 threads, 4x4 per thread.
__global__ __launch_bounds__(256) void bitgemm(
    const uint32_t* __restrict__ Abits, int aStride, size_t aRowBase,
    const float* __restrict__ Bmat, int K,
    const float* __restrict__ bias,
    double* __restrict__ C, int ldc) {
  __shared__ uint32_t sA[64];
  __shared__ float sB[32][65];
  int tid = threadIdx.x;
  int tx = tid & 15;        // col group
  int ty = tid >> 4;        // row group
  size_t row0 = (size_t)blockIdx.x * 64;
  int col0 = blockIdx.y * 64;
  double acc[4][4] = {{0.0}};
  int nw = (K + 31) / 32;
  for (int w = 0; w < nw; ++w) {
    __syncthreads();
    if (tid < 64) sA[tid] = Abits[(aRowBase + row0 + tid) * (size_t)aStride + w];
    for (int l = tid; l < 64 * 32; l += 256) {
      int o = l >> 5, kk = l & 31;
      int f = w * 32 + kk;
      sB[kk][o] = (f < K) ? Bmat[(size_t)(col0 + o) * K + f] : 0.0f;
    }
    __syncthreads();
    uint32_t aw[4];
#pragma unroll
    for (int i = 0; i < 4; ++i) aw[i] = sA[ty * 4 + i];
#pragma unroll 4
    for (int kk = 0; kk < 32; ++kk) {
      double bv[4];
#pragma unroll
      for (int j = 0; j < 4; ++j) bv[j] = (double)sB[kk][tx * 4 + j];
#pragma unroll
      for (int i = 0; i < 4; ++i) {
        double a = (double)((aw[i] >> kk) & 1u);
#pragma unroll
        for (int j = 0; j < 4; ++j) acc[i][j] = fma(a, bv[j], acc[i][j]);
      }
    }
  }
#pragma unroll
  for (int i = 0; i < 4; ++i) {
#pragma unroll
    for (int j = 0; j < 4; ++j) {
      int col = col0 + tx * 4 + j;
      C[(row0 + ty * 4 + i) * (size_t)ldc + col] = acc[i][j] + (double)bias[col];
    }
  }
}

// LIF over T steps for layer 1 (one block per batch row of this chunk, 512 threads = H1 neurons).
// Emits spike bits packed along o.
__global__ __launch_bounds__(512) void lif1(const double* __restrict__ inp1,
                                            uint32_t* __restrict__ spk1, int bBase) {
  int b_local = blockIdx.x;
  int o = threadIdx.x;          // 0..511
  int b = bBase + b_local;
  double mem = 0.0;
  for (int t = 0; t < Tst; ++t) {
    double inp = inp1[((size_t)(b_local * Tst + t)) * H1 + o];
    mem = mem + (inp - mem) / 2.0;
    bool spk = (mem >= 1.0);
    unsigned long long m = __ballot(spk);
    if ((o & 63) == 0) {
      int wv = o >> 6;
      size_t base = ((size_t)(b * Tst + t)) * (H1 / 32);
      spk1[base + wv * 2]     = (uint32_t)(m & 0xffffffffu);
      spk1[base + wv * 2 + 1] = (uint32_t)(m >> 32);
    }
    if (spk) mem = 0.0;
  }
}

// LIF layer 2: one block per batch row, 128 threads; write final (post-reset) membrane.
__global__ __launch_bounds__(128) void lif2(const double* __restrict__ inp2,
                                            double* __restrict__ mem2) {
  int b = blockIdx.x;
  int o = threadIdx.x;          // 0..127
  double mem = 0.0;
  for (int t = 0; t < Tst; ++t) {
    double inp = inp2[((size_t)(b * Tst + t)) * H2 + o];
    mem = mem + (inp - mem) / 2.0;
    if (mem >= 1.0) mem = 0.0;
  }
  mem2[(size_t)b * H2 + o] = mem;
}

// out = mem2 @ Wd^T + bd   (4096x128 x 128x10)
__global__ void finalk(const double* __restrict__ mem2, const float* __restrict__ Wd,
                       const float* __restrict__ bd, float* __restrict__ out) {
  int gid = blockIdx.x * blockDim.x + threadIdx.x;
  if (gid >= Bsz * NOUT) return;
  int b = gid / NOUT, j = gid % NOUT;
  double s = (double)bd[j];
  const double* m = mem2 + (size_t)b * H2;
  const float* wr = Wd + (size_t)j * H2;
  for (int k = 0; k < H2; ++k) s = fma(m[k], (double)wr[k], s);
  out[gid] = (float)s;
}

extern "C" void kernel_launch(void* const* d_in, const int* in_sizes, int n_in,
                              void* d_out, int out_size, void* d_ws, size_t ws_size,
                              hipStream_t stream) {
  const float* x  = (const float*)d_in[0];
  const float* W1 = (const float*)d_in[1];
  const float* b1 = (const float*)d_in[2];
  const float* W2 = (const float*)d_in[3];
  const float* b2 = (const float*)d_in[4];
  const float* Wd = (const float*)d_in[5];
  const float* bd = (const float*)d_in[6];
  float* out = (float*)d_out;

  char* ws = (char*)d_ws;
  // Layout (bytes):
  //   inp_buf : 20480*512*8 = 83,886,080   (reused: layer-1 chunk inp, then full layer-2 inp 81920*128*8 same size)
  //   mem2    : 4096*128*8  =  4,194,304
  //   sbits   : 81920*64*4  = 20,971,520
  //   spk1    : 81920*16*4  =  5,242,880
  double*   inp_buf = (double*)ws;
  double*   mem2    = (double*)(ws + 83886080ull);
  uint32_t* sbits   = (uint32_t*)(ws + 83886080ull + 4194304ull);
  uint32_t* spk1    = (uint32_t*)(ws + 83886080ull + 4194304ull + 20971520ull);

  // 1) exact Poisson spike train (bit-packed), partitionable-threefry semantics
  {
    int threads = Bsz * Tst * FW;
    spikegen<<<dim3((threads + 255) / 256), dim3(256), 0, stream>>>(x, sbits);
  }

  // 2) layer 1 in 4 chunks of 1024 batch rows: bit-GEMM (f64) then LIF -> spike bits
  for (int cb = 0; cb < 4; ++cb) {
    size_t rowBase = (size_t)cb * CHUNK * Tst;  // 20480 per chunk
    bitgemm<<<dim3((CHUNK * Tst) / 64, H1 / 64), dim3(256), 0, stream>>>(
        sbits, FW, rowBase, W1, Fin, b1, inp_buf, H1);
    lif1<<<dim3(CHUNK), dim3(H1), 0, stream>>>(inp_buf, spk1, cb * CHUNK);
  }

  // 3) layer 2 GEMM over all rows (reuses inp_buf), then LIF to final membrane
  bitgemm<<<dim3((Bsz * Tst) / 64, H2 / 64), dim3(256), 0, stream>>>(
      spk1, H1 / 32, 0, W2, H1, b2, inp_buf, H2);
  lif2<<<dim3(Bsz), dim3(H2), 0, stream>>>(inp_buf, mem2);

  // 4) readout
  finalk<<<dim3((Bsz * NOUT + 255) / 256), dim3(256), 0, stream>>>(mem2, Wd, bd, out);
}